// Round 1
// baseline (352.703 us; speedup 1.0000x reference)
//
#include <hip/hip_runtime.h>

#define D_MODEL 768
#define S_LEN   2048
#define BATCH   2
#define NHEAD   12
#define DH      64
#define NTOK    (BATCH * S_LEN)   // 4096

typedef __attribute__((ext_vector_type(8))) short bf16x8;   // 8 bf16 in 4 VGPRs
typedef __attribute__((ext_vector_type(4))) float f32x4;

__device__ inline unsigned short f2bf(float f) {
    union { float f; unsigned u; } v; v.f = f;
    unsigned u = v.u;
    u += 0x7fffu + ((u >> 16) & 1u);   // round-to-nearest-even
    return (unsigned short)(u >> 16);
}

// ---------------------------------------------------------------------------
// Kernel 1: convert X (=Q input) and the 4 weight matrices fp32 -> bf16
// ---------------------------------------------------------------------------
__global__ __launch_bounds__(256) void convert_kernel(
    const float* __restrict__ Q,
    const float* __restrict__ Wq, const float* __restrict__ Wk,
    const float* __restrict__ Wv, const float* __restrict__ Wo,
    unsigned short* __restrict__ Xb,
    unsigned short* __restrict__ Wqb, unsigned short* __restrict__ Wkb,
    unsigned short* __restrict__ Wvb, unsigned short* __restrict__ Wob)
{
    const int XV = NTOK * D_MODEL / 4;     // 786432 float4s
    const int WV = D_MODEL * D_MODEL / 4;  // 147456 float4s
    int idx = blockIdx.x * 256 + threadIdx.x;
    if (idx >= XV + 4 * WV) return;

    const float* src; unsigned short* dst; int off;
    if (idx < XV) { src = Q; dst = Xb; off = idx; }
    else {
        int i2 = idx - XV;
        int seg = i2 / WV; off = i2 - seg * WV;
        if      (seg == 0) { src = Wq; dst = Wqb; }
        else if (seg == 1) { src = Wk; dst = Wkb; }
        else if (seg == 2) { src = Wv; dst = Wvb; }
        else               { src = Wo; dst = Wob; }
    }
    float4 v = reinterpret_cast<const float4*>(src)[off];
    ushort4 o;
    o.x = f2bf(v.x); o.y = f2bf(v.y); o.z = f2bf(v.z); o.w = f2bf(v.w);
    reinterpret_cast<ushort4*>(dst)[off] = o;
}

// ---------------------------------------------------------------------------
// Kernel 2: QKV projection.  Y = X @ W^T + b  (torch Linear)
// Block = 4 waves, computes 64 rows x 64 cols. blockIdx.z picks q/k/v.
// q,k written [b,h,s,d]; v written transposed [b,h,d,s].
// ---------------------------------------------------------------------------
__global__ __launch_bounds__(256) void qkv_gemm_kernel(
    const unsigned short* __restrict__ Xb,
    const unsigned short* __restrict__ Wqb, const unsigned short* __restrict__ Wkb,
    const unsigned short* __restrict__ Wvb,
    const float* __restrict__ bq, const float* __restrict__ bk,
    const float* __restrict__ bv,
    unsigned short* __restrict__ qb, unsigned short* __restrict__ kb,
    unsigned short* __restrict__ vtb)
{
    const int which = blockIdx.z;
    const unsigned short* W = (which == 0) ? Wqb : (which == 1) ? Wkb : Wvb;
    const float* bias        = (which == 0) ? bq  : (which == 1) ? bk  : bv;

    const int lane = threadIdx.x & 63;
    const int wv   = threadIdx.x >> 6;
    const int lr   = lane & 15;      // fragment row/col within 16
    const int lg   = lane >> 4;      // k-group 0..3
    const int row0 = blockIdx.y * 64 + wv * 16;
    const int col0 = blockIdx.x * 64;

    f32x4 acc[4] = {};
    for (int k0 = 0; k0 < D_MODEL; k0 += 32) {
        bf16x8 a = *reinterpret_cast<const bf16x8*>(
            Xb + (size_t)(row0 + lr) * D_MODEL + k0 + lg * 8);
#pragma unroll
        for (int t = 0; t < 4; ++t) {
            bf16x8 b = *reinterpret_cast<const bf16x8*>(
                W + (size_t)(col0 + t * 16 + lr) * D_MODEL + k0 + lg * 8);
            acc[t] = __builtin_amdgcn_mfma_f32_16x16x32_bf16(a, b, acc[t], 0, 0, 0);
        }
    }

#pragma unroll
    for (int t = 0; t < 4; ++t) {
        int col = col0 + t * 16 + lr;
        float bval = bias[col];
        int h = col >> 6, d = col & 63;
#pragma unroll
        for (int r = 0; r < 4; ++r) {
            int row = row0 + lg * 4 + r;       // token index
            int bb = row >> 11, s = row & 2047;
            unsigned short o = f2bf(acc[t][r] + bval);
            if (which == 2)
                vtb[((size_t)(bb * NHEAD + h) * DH + d) * S_LEN + s] = o;
            else {
                size_t off = ((size_t)(bb * NHEAD + h) * S_LEN + s) * DH + d;
                if (which == 0) qb[off] = o; else kb[off] = o;
            }
        }
    }
}

// ---------------------------------------------------------------------------
// Kernel 3: attention.  grid = (S/64, B*H). 4 waves, each wave owns 16 q-rows
// and loops over all keys in chunks of 32 with online softmax.
// ---------------------------------------------------------------------------
__global__ __launch_bounds__(256) void attn_kernel(
    const unsigned short* __restrict__ qb, const unsigned short* __restrict__ kb,
    const unsigned short* __restrict__ vtb,
    unsigned short* __restrict__ attnb)
{
    const int lane = threadIdx.x & 63;
    const int wv   = threadIdx.x >> 6;
    const int lr   = lane & 15;
    const int lg   = lane >> 4;
    const int bh   = blockIdx.y;            // b*NHEAD + h
    const int h    = bh % NHEAD, bb = bh / NHEAD;
    const int q0   = blockIdx.x * 64 + wv * 16;

    __shared__ __align__(16) unsigned short P[4][16][40]; // stride 80B: aligned b128 reads

    const unsigned short* qptr = qb  + ((size_t)bh * S_LEN + q0) * DH;
    const unsigned short* kptr = kb  + (size_t)bh * S_LEN * DH;
    const unsigned short* vptr = vtb + (size_t)bh * DH * S_LEN;

    bf16x8 aq0 = *reinterpret_cast<const bf16x8*>(qptr + (size_t)lr * DH + lg * 8);
    bf16x8 aq1 = *reinterpret_cast<const bf16x8*>(qptr + (size_t)lr * DH + 32 + lg * 8);

    float m[4], l[4];
    f32x4 acc[4] = {};
#pragma unroll
    for (int r = 0; r < 4; ++r) { m[r] = -1e30f; l[r] = 0.f; }

    for (int c = 0; c < S_LEN; c += 32) {
        // ---- scores: two 16-key sub-tiles ----
        f32x4 s0 = {}, s1 = {};
        {
            const unsigned short* kp = kptr + (size_t)(c + lr) * DH;
            bf16x8 b0 = *reinterpret_cast<const bf16x8*>(kp + lg * 8);
            bf16x8 b1 = *reinterpret_cast<const bf16x8*>(kp + 32 + lg * 8);
            s0 = __builtin_amdgcn_mfma_f32_16x16x32_bf16(aq0, b0, s0, 0, 0, 0);
            s0 = __builtin_amdgcn_mfma_f32_16x16x32_bf16(aq1, b1, s0, 0, 0, 0);
        }
        {
            const unsigned short* kp = kptr + (size_t)(c + 16 + lr) * DH;
            bf16x8 b0 = *reinterpret_cast<const bf16x8*>(kp + lg * 8);
            bf16x8 b1 = *reinterpret_cast<const bf16x8*>(kp + 32 + lg * 8);
            s1 = __builtin_amdgcn_mfma_f32_16x16x32_bf16(aq0, b0, s1, 0, 0, 0);
            s1 = __builtin_amdgcn_mfma_f32_16x16x32_bf16(aq1, b1, s1, 0, 0, 0);
        }
        // ---- online softmax (rows live in-lane: row = lg*4 + r) ----
        float p0[4], p1[4], sf[4];
#pragma unroll
        for (int r = 0; r < 4; ++r) {
            float a0 = s0[r] * 0.125f, a1 = s1[r] * 0.125f;
            float mx = fmaxf(a0, a1);
            mx = fmaxf(mx, __shfl_xor(mx, 1));
            mx = fmaxf(mx, __shfl_xor(mx, 2));
            mx = fmaxf(mx, __shfl_xor(mx, 4));
            mx = fmaxf(mx, __shfl_xor(mx, 8));
            float mn = fmaxf(m[r], mx);
            p0[r] = __expf(a0 - mn);
            p1[r] = __expf(a1 - mn);
            float ps = p0[r] + p1[r];
            ps += __shfl_xor(ps, 1); ps += __shfl_xor(ps, 2);
            ps += __shfl_xor(ps, 4); ps += __shfl_xor(ps, 8);
            sf[r] = __expf(m[r] - mn);
            l[r] = l[r] * sf[r] + ps;
            m[r] = mn;
        }
#pragma unroll
        for (int t = 0; t < 4; ++t)
#pragma unroll
            for (int r = 0; r < 4; ++r) acc[t][r] *= sf[r];

        // ---- P -> LDS (transpose to A-fragment layout) ----
#pragma unroll
        for (int r = 0; r < 4; ++r) {
            P[wv][lg * 4 + r][lr]      = f2bf(p0[r]);
            P[wv][lg * 4 + r][16 + lr] = f2bf(p1[r]);
        }
        bf16x8 ap = *reinterpret_cast<const bf16x8*>(&P[wv][lr][lg * 8]);

        // ---- PV: out[q,d] += P[q,s] * v[s,d], B from transposed v ----
#pragma unroll
        for (int t = 0; t < 4; ++t) {
            bf16x8 bvf = *reinterpret_cast<const bf16x8*>(
                vptr + (size_t)(t * 16 + lr) * S_LEN + c + lg * 8);
            acc[t] = __builtin_amdgcn_mfma_f32_16x16x32_bf16(ap, bvf, acc[t], 0, 0, 0);
        }
    }

    // ---- epilogue: normalize and store bf16 [token][h*64+d] ----
#pragma unroll
    for (int t = 0; t < 4; ++t) {
#pragma unroll
        for (int r = 0; r < 4; ++r) {
            int srow = q0 + lg * 4 + r;
            int col  = h * DH + t * 16 + lr;
            attnb[((size_t)(bb * S_LEN + srow)) * D_MODEL + col] = f2bf(acc[t][r] / l[r]);
        }
    }
}

// ---------------------------------------------------------------------------
// Kernel 4: output projection + bias + residual -> fp32 Y
// ---------------------------------------------------------------------------
__global__ __launch_bounds__(256) void oproj_kernel(
    const unsigned short* __restrict__ attnb, const unsigned short* __restrict__ Wob,
    const float* __restrict__ bo, const float* __restrict__ Qres,
    float* __restrict__ Y)
{
    const int lane = threadIdx.x & 63;
    const int wv   = threadIdx.x >> 6;
    const int lr   = lane & 15;
    const int lg   = lane >> 4;
    const int row0 = blockIdx.y * 64 + wv * 16;
    const int col0 = blockIdx.x * 64;

    f32x4 acc[4] = {};
    for (int k0 = 0; k0 < D_MODEL; k0 += 32) {
        bf16x8 a = *reinterpret_cast<const bf16x8*>(
            attnb + (size_t)(row0 + lr) * D_MODEL + k0 + lg * 8);
#pragma unroll
        for (int t = 0; t < 4; ++t) {
            bf16x8 b = *reinterpret_cast<const bf16x8*>(
                Wob + (size_t)(col0 + t * 16 + lr) * D_MODEL + k0 + lg * 8);
            acc[t] = __builtin_amdgcn_mfma_f32_16x16x32_bf16(a, b, acc[t], 0, 0, 0);
        }
    }
#pragma unroll
    for (int t = 0; t < 4; ++t) {
        int col = col0 + t * 16 + lr;
        float bval = bo[col];
#pragma unroll
        for (int r = 0; r < 4; ++r) {
            int row = row0 + lg * 4 + r;
            size_t off = (size_t)row * D_MODEL + col;
            Y[off] = acc[t][r] + bval + Qres[off];
        }
    }
}

// ---------------------------------------------------------------------------
// Kernel 5: LayerNorm per row.  1 wave per row, 4 rows per block.
// ---------------------------------------------------------------------------
__global__ __launch_bounds__(256) void ln_kernel(
    const float* __restrict__ Y,
    const float* __restrict__ gamma, const float* __restrict__ beta,
    float* __restrict__ out)
{
    const int lane = threadIdx.x & 63;
    const int row  = blockIdx.x * 4 + (threadIdx.x >> 6);
    const float4* yr = reinterpret_cast<const float4*>(Y + (size_t)row * D_MODEL);

    float4 v[3];
    float sum = 0.f, ss = 0.f;
#pragma unroll
    for (int j = 0; j < 3; ++j) {
        v[j] = yr[lane + 64 * j];
        sum += v[j].x + v[j].y + v[j].z + v[j].w;
        ss  += v[j].x * v[j].x + v[j].y * v[j].y + v[j].z * v[j].z + v[j].w * v[j].w;
    }
#pragma unroll
    for (int msk = 1; msk < 64; msk <<= 1) {
        sum += __shfl_xor(sum, msk);
        ss  += __shfl_xor(ss,  msk);
    }
    float mu  = sum * (1.f / 768.f);
    float var = ss * (1.f / 768.f) - mu * mu;
    float is  = rsqrtf(var + 1e-5f);

    const float4* g4 = reinterpret_cast<const float4*>(gamma);
    const float4* b4 = reinterpret_cast<const float4*>(beta);
    float4* o4 = reinterpret_cast<float4*>(out + (size_t)row * D_MODEL);
#pragma unroll
    for (int j = 0; j < 3; ++j) {
        float4 g = g4[lane + 64 * j], b = b4[lane + 64 * j], r;
        r.x = (v[j].x - mu) * is * g.x + b.x;
        r.y = (v[j].y - mu) * is * g.y + b.y;
        r.z = (v[j].z - mu) * is * g.z + b.z;
        r.w = (v[j].w - mu) * is * g.w + b.w;
        o4[lane + 64 * j] = r;
    }
}

// ---------------------------------------------------------------------------
extern "C" void kernel_launch(void* const* d_in, const int* in_sizes, int n_in,
                              void* d_out, int out_size, void* d_ws, size_t ws_size,
                              hipStream_t stream)
{
    const float* Q     = (const float*)d_in[0];
    const float* Wq    = (const float*)d_in[1];
    const float* bq    = (const float*)d_in[2];
    const float* Wk    = (const float*)d_in[3];
    const float* bk    = (const float*)d_in[4];
    const float* Wv    = (const float*)d_in[5];
    const float* bv    = (const float*)d_in[6];
    const float* Wo    = (const float*)d_in[7];
    const float* bo    = (const float*)d_in[8];
    const float* gamma = (const float*)d_in[9];
    const float* beta  = (const float*)d_in[10];
    float* out = (float*)d_out;

    char* ws = (char*)d_ws;
    // workspace layout (bytes, all 256-aligned)
    unsigned short* Xb    = (unsigned short*)(ws + 0);          // 6291456
    unsigned short* Wqb   = (unsigned short*)(ws + 6291456);    // 1179648
    unsigned short* Wkb   = (unsigned short*)(ws + 7471104);
    unsigned short* Wvb   = (unsigned short*)(ws + 8650752);
    unsigned short* Wob   = (unsigned short*)(ws + 9830400);
    unsigned short* qb    = (unsigned short*)(ws + 11010048);   // 6291456
    unsigned short* kb    = (unsigned short*)(ws + 17301504);
    unsigned short* vtb   = (unsigned short*)(ws + 23592960);
    unsigned short* attnb = (unsigned short*)(ws + 29884416);
    float*          Yf    = (float*)        (ws + 36175872);    // 12582912
    // total: 48758784 bytes

    convert_kernel<<<5376, 256, 0, stream>>>(Q, Wq, Wk, Wv, Wo, Xb, Wqb, Wkb, Wvb, Wob);
    qkv_gemm_kernel<<<dim3(12, 64, 3), 256, 0, stream>>>(Xb, Wqb, Wkb, Wvb,
                                                         bq, bk, bv, qb, kb, vtb);
    attn_kernel<<<dim3(32, 24), 256, 0, stream>>>(qb, kb, vtb, attnb);
    oproj_kernel<<<dim3(12, 64), 256, 0, stream>>>(attnb, Wob, bo, Q, Yf);
    ln_kernel<<<1024, 256, 0, stream>>>(Yf, gamma, beta, out);
}

// Round 2
// 336.339 us; speedup vs baseline: 1.0487x; 1.0487x over previous
//
#include <hip/hip_runtime.h>
#include <hip/hip_bf16.h>

#define D_MODEL 768
#define S_LEN   2048
#define BATCH   2
#define NHEAD   12
#define DH      64
#define NTOK    (BATCH * S_LEN)   // 4096

typedef __attribute__((ext_vector_type(8))) short bf16x8;   // 8 bf16 in 4 VGPRs
typedef __attribute__((ext_vector_type(4))) float f32x4;

__device__ inline unsigned short f2bf(float f) {
    union { float f; unsigned u; } v; v.f = f;
    unsigned u = v.u;
    u += 0x7fffu + ((u >> 16) & 1u);   // round-to-nearest-even
    return (unsigned short)(u >> 16);
}

__device__ inline unsigned pack_bf2(float a, float b) {
    union { __hip_bfloat162 h2; unsigned u; } cv;
    cv.h2 = __float22bfloat162_rn(make_float2(a, b));   // v_cvt_pk_bf16_f32
    return cv.u;
}

// ---------------------------------------------------------------------------
// Kernel 1: convert X (=Q input) and the 4 weight matrices fp32 -> bf16
// ---------------------------------------------------------------------------
__global__ __launch_bounds__(256) void convert_kernel(
    const float* __restrict__ Q,
    const float* __restrict__ Wq, const float* __restrict__ Wk,
    const float* __restrict__ Wv, const float* __restrict__ Wo,
    unsigned short* __restrict__ Xb,
    unsigned short* __restrict__ Wqb, unsigned short* __restrict__ Wkb,
    unsigned short* __restrict__ Wvb, unsigned short* __restrict__ Wob)
{
    const int XV = NTOK * D_MODEL / 4;
    const int WV = D_MODEL * D_MODEL / 4;
    int idx = blockIdx.x * 256 + threadIdx.x;
    if (idx >= XV + 4 * WV) return;

    const float* src; unsigned short* dst; int off;
    if (idx < XV) { src = Q; dst = Xb; off = idx; }
    else {
        int i2 = idx - XV;
        int seg = i2 / WV; off = i2 - seg * WV;
        if      (seg == 0) { src = Wq; dst = Wqb; }
        else if (seg == 1) { src = Wk; dst = Wkb; }
        else if (seg == 2) { src = Wv; dst = Wvb; }
        else               { src = Wo; dst = Wob; }
    }
    float4 v = reinterpret_cast<const float4*>(src)[off];
    uint2 o;
    o.x = pack_bf2(v.x, v.y);
    o.y = pack_bf2(v.z, v.w);
    reinterpret_cast<uint2*>(dst)[off] = o;
}

// ---------------------------------------------------------------------------
// Kernel 2: QKV projection.  Y = X @ W^T + b.  Wave: 32 rows x 128 cols.
// Block = 4 waves -> 128x128.  q,k [b,h,s,d]; v transposed [b,h,d,s].
// ---------------------------------------------------------------------------
__global__ __launch_bounds__(256) void qkv_gemm_kernel(
    const unsigned short* __restrict__ Xb,
    const unsigned short* __restrict__ Wqb, const unsigned short* __restrict__ Wkb,
    const unsigned short* __restrict__ Wvb,
    const float* __restrict__ bq, const float* __restrict__ bk,
    const float* __restrict__ bv,
    unsigned short* __restrict__ qb, unsigned short* __restrict__ kb,
    unsigned short* __restrict__ vtb)
{
    const int which = blockIdx.z;
    const unsigned short* W = (which == 0) ? Wqb : (which == 1) ? Wkb : Wvb;
    const float* bias        = (which == 0) ? bq  : (which == 1) ? bk  : bv;

    const int lane = threadIdx.x & 63;
    const int wv   = threadIdx.x >> 6;
    const int lr   = lane & 15;
    const int lg   = lane >> 4;
    const int row0 = blockIdx.y * 128 + wv * 32;
    const int col0 = blockIdx.x * 128;

    f32x4 acc[2][8] = {};
    for (int k0 = 0; k0 < D_MODEL; k0 += 32) {
        bf16x8 a0 = *reinterpret_cast<const bf16x8*>(
            Xb + (size_t)(row0 + lr) * D_MODEL + k0 + lg * 8);
        bf16x8 a1 = *reinterpret_cast<const bf16x8*>(
            Xb + (size_t)(row0 + 16 + lr) * D_MODEL + k0 + lg * 8);
#pragma unroll
        for (int t = 0; t < 8; ++t) {
            bf16x8 b = *reinterpret_cast<const bf16x8*>(
                W + (size_t)(col0 + t * 16 + lr) * D_MODEL + k0 + lg * 8);
            acc[0][t] = __builtin_amdgcn_mfma_f32_16x16x32_bf16(a0, b, acc[0][t], 0, 0, 0);
            acc[1][t] = __builtin_amdgcn_mfma_f32_16x16x32_bf16(a1, b, acc[1][t], 0, 0, 0);
        }
    }

#pragma unroll
    for (int i = 0; i < 2; ++i) {
#pragma unroll
        for (int t = 0; t < 8; ++t) {
            int col = col0 + t * 16 + lr;
            float bval = bias[col];
            int h = col >> 6, d = col & 63;
            int row0i = row0 + i * 16 + lg * 4;     // 4 consecutive rows
            int bb = row0i >> 11, s0 = row0i & 2047;
            if (which == 2) {
                uint2 w;
                w.x = pack_bf2(acc[i][t][0] + bval, acc[i][t][1] + bval);
                w.y = pack_bf2(acc[i][t][2] + bval, acc[i][t][3] + bval);
                *reinterpret_cast<uint2*>(
                    vtb + ((size_t)(bb * NHEAD + h) * DH + d) * S_LEN + s0) = w;
            } else {
                unsigned short* dst = (which == 0) ? qb : kb;
#pragma unroll
                for (int r = 0; r < 4; ++r)
                    dst[((size_t)(bb * NHEAD + h) * S_LEN + s0 + r) * DH + d] =
                        f2bf(acc[i][t][r] + bval);
            }
        }
    }
}

// ---------------------------------------------------------------------------
// Kernel 3: attention, swapped-operand form.  grid = (S/64, B*H), 4 waves.
// Each wave owns 16 q-rows (q = lane&15), loops keys in chunks of 64.
// S^T = mfma(K, Q): lane holds 16 scores of ONE q-row -> in-lane softmax.
// out^T = mfma(V^T, P^T): scale factor stays lane-local.
// ---------------------------------------------------------------------------
__global__ __launch_bounds__(256) void attn_kernel(
    const unsigned short* __restrict__ qb, const unsigned short* __restrict__ kb,
    const unsigned short* __restrict__ vtb,
    unsigned short* __restrict__ attnb)
{
    const int lane = threadIdx.x & 63;
    const int wv   = threadIdx.x >> 6;
    const int lr   = lane & 15;     // q-row within tile / n-index
    const int lg   = lane >> 4;     // k-group
    const int bh   = blockIdx.y;
    const int h    = bh % NHEAD, bb = bh / NHEAD;
    const int q0   = blockIdx.x * 64 + wv * 16;

    // per-wave P tile: [q][k] 16x64 bf16, stride 68 (+4 pad) for banking
    __shared__ __align__(16) unsigned short PL[4][16][68];

    const unsigned short* qptr = qb  + ((size_t)bh * S_LEN + q0) * DH;
    const unsigned short* kptr = kb  + (size_t)bh * S_LEN * DH;
    const unsigned short* vptr = vtb + (size_t)bh * DH * S_LEN;

    // Q as B-operand: lane holds Q[q=lr][d = lg*8..+7] (+32 for second half)
    bf16x8 bq0 = *reinterpret_cast<const bf16x8*>(qptr + (size_t)lr * DH + lg * 8);
    bf16x8 bq1 = *reinterpret_cast<const bf16x8*>(qptr + (size_t)lr * DH + 32 + lg * 8);

    float m = -1e30f, l = 0.f;      // for q = q0+lr (replicated across lg)
    f32x4 acc[4] = {};              // acc[t][r] = outT[d=t*16+lg*4+r][q=lr]
    const float SC = 0.125f * 1.44269504088896f;  // 1/sqrt(64) * log2(e)

    for (int c = 0; c < S_LEN; c += 64) {
        // ---- S^T: 4 sub-tiles of 16 keys ----
        f32x4 s[4] = {};
#pragma unroll
        for (int kt = 0; kt < 4; ++kt) {
            const unsigned short* kp = kptr + (size_t)(c + kt * 16 + lr) * DH;
            bf16x8 ak0 = *reinterpret_cast<const bf16x8*>(kp + lg * 8);
            bf16x8 ak1 = *reinterpret_cast<const bf16x8*>(kp + 32 + lg * 8);
            s[kt] = __builtin_amdgcn_mfma_f32_16x16x32_bf16(ak0, bq0, s[kt], 0, 0, 0);
            s[kt] = __builtin_amdgcn_mfma_f32_16x16x32_bf16(ak1, bq1, s[kt], 0, 0, 0);
        }

        // ---- V fragments issued early (hide latency under softmax) ----
        bf16x8 av0[4], av1[4];
#pragma unroll
        for (int t = 0; t < 4; ++t) {
            const unsigned short* vp = vptr + (size_t)(t * 16 + lr) * S_LEN + c + lg * 8;
            av0[t] = *reinterpret_cast<const bf16x8*>(vp);
            av1[t] = *reinterpret_cast<const bf16x8*>(vp + 32);
        }

        // ---- in-lane online softmax over 16 values ----
        float p[16];
#pragma unroll
        for (int kt = 0; kt < 4; ++kt)
#pragma unroll
            for (int r = 0; r < 4; ++r) p[kt * 4 + r] = s[kt][r] * SC;

        float mx01 = fmaxf(fmaxf(p[0], p[1]), fmaxf(p[2], p[3]));
        float mx23 = fmaxf(fmaxf(p[4], p[5]), fmaxf(p[6], p[7]));
        float mx45 = fmaxf(fmaxf(p[8], p[9]), fmaxf(p[10], p[11]));
        float mx67 = fmaxf(fmaxf(p[12], p[13]), fmaxf(p[14], p[15]));
        float mx = fmaxf(fmaxf(mx01, mx23), fmaxf(mx45, mx67));
        mx = fmaxf(mx, __shfl_xor(mx, 16));
        mx = fmaxf(mx, __shfl_xor(mx, 32));
        float mn = fmaxf(m, mx);

        float sum = 0.f;
#pragma unroll
        for (int j = 0; j < 16; ++j) {
            p[j] = __builtin_amdgcn_exp2f(p[j] - mn);
            sum += p[j];
        }
        sum += __shfl_xor(sum, 16);
        sum += __shfl_xor(sum, 32);
        float sf = __builtin_amdgcn_exp2f(m - mn);
        l = l * sf + sum; m = mn;
#pragma unroll
        for (int t = 0; t < 4; ++t) acc[t] *= sf;

        // ---- P -> LDS (lane's 16 values -> rows of PL[q][k]) ----
#pragma unroll
        for (int kt = 0; kt < 4; ++kt) {
            uint2 w;
            w.x = pack_bf2(p[kt * 4 + 0], p[kt * 4 + 1]);
            w.y = pack_bf2(p[kt * 4 + 2], p[kt * 4 + 3]);
            *reinterpret_cast<uint2*>(&PL[wv][lr][kt * 16 + lg * 4]) = w;
        }

        // ---- read P^T B-fragments (intra-wave, no barrier needed) ----
        union { bf16x8 v; uint2 u[2]; } bp0, bp1;
        bp0.u[0] = *reinterpret_cast<const uint2*>(&PL[wv][lr][lg * 8]);
        bp0.u[1] = *reinterpret_cast<const uint2*>(&PL[wv][lr][lg * 8 + 4]);
        bp1.u[0] = *reinterpret_cast<const uint2*>(&PL[wv][lr][32 + lg * 8]);
        bp1.u[1] = *reinterpret_cast<const uint2*>(&PL[wv][lr][32 + lg * 8 + 4]);

        // ---- PV: outT[d][q] += V^T[d][k] * P[q][k] ----
#pragma unroll
        for (int t = 0; t < 4; ++t) {
            acc[t] = __builtin_amdgcn_mfma_f32_16x16x32_bf16(av0[t], bp0.v, acc[t], 0, 0, 0);
            acc[t] = __builtin_amdgcn_mfma_f32_16x16x32_bf16(av1[t], bp1.v, acc[t], 0, 0, 0);
        }
    }

    // ---- epilogue: lane owns q = q0+lr; normalize, store bf16 pairs ----
    float rl = 1.0f / l;
    size_t rowbase = ((size_t)(bb * S_LEN + q0 + lr)) * D_MODEL + h * DH;
#pragma unroll
    for (int t = 0; t < 4; ++t) {
        unsigned w0 = pack_bf2(acc[t][0] * rl, acc[t][1] * rl);
        unsigned w1 = pack_bf2(acc[t][2] * rl, acc[t][3] * rl);
        *reinterpret_cast<unsigned*>(attnb + rowbase + t * 16 + lg * 4)     = w0;
        *reinterpret_cast<unsigned*>(attnb + rowbase + t * 16 + lg * 4 + 2) = w1;
    }
}

// ---------------------------------------------------------------------------
// Kernel 4: output projection + bias + residual -> fp32 Y.  32x128 per wave.
// ---------------------------------------------------------------------------
__global__ __launch_bounds__(256) void oproj_kernel(
    const unsigned short* __restrict__ attnb, const unsigned short* __restrict__ Wob,
    const float* __restrict__ bo, const float* __restrict__ Qres,
    float* __restrict__ Y)
{
    const int lane = threadIdx.x & 63;
    const int wv   = threadIdx.x >> 6;
    const int lr   = lane & 15;
    const int lg   = lane >> 4;
    const int row0 = blockIdx.y * 128 + wv * 32;
    const int col0 = blockIdx.x * 128;

    f32x4 acc[2][8] = {};
    for (int k0 = 0; k0 < D_MODEL; k0 += 32) {
        bf16x8 a0 = *reinterpret_cast<const bf16x8*>(
            attnb + (size_t)(row0 + lr) * D_MODEL + k0 + lg * 8);
        bf16x8 a1 = *reinterpret_cast<const bf16x8*>(
            attnb + (size_t)(row0 + 16 + lr) * D_MODEL + k0 + lg * 8);
#pragma unroll
        for (int t = 0; t < 8; ++t) {
            bf16x8 b = *reinterpret_cast<const bf16x8*>(
                Wob + (size_t)(col0 + t * 16 + lr) * D_MODEL + k0 + lg * 8);
            acc[0][t] = __builtin_amdgcn_mfma_f32_16x16x32_bf16(a0, b, acc[0][t], 0, 0, 0);
            acc[1][t] = __builtin_amdgcn_mfma_f32_16x16x32_bf16(a1, b, acc[1][t], 0, 0, 0);
        }
    }
#pragma unroll
    for (int i = 0; i < 2; ++i)
#pragma unroll
        for (int t = 0; t < 8; ++t) {
            int col = col0 + t * 16 + lr;
            float bval = bo[col];
#pragma unroll
            for (int r = 0; r < 4; ++r) {
                int row = row0 + i * 16 + lg * 4 + r;
                size_t off = (size_t)row * D_MODEL + col;
                Y[off] = acc[i][t][r] + bval + Qres[off];
            }
        }
}

// ---------------------------------------------------------------------------
// Kernel 5: LayerNorm per row.  1 wave per row, 4 rows per block.
// ---------------------------------------------------------------------------
__global__ __launch_bounds__(256) void ln_kernel(
    const float* __restrict__ Y,
    const float* __restrict__ gamma, const float* __restrict__ beta,
    float* __restrict__ out)
{
    const int lane = threadIdx.x & 63;
    const int row  = blockIdx.x * 4 + (threadIdx.x >> 6);
    const float4* yr = reinterpret_cast<const float4*>(Y + (size_t)row * D_MODEL);

    float4 v[3];
    float sum = 0.f, ss = 0.f;
#pragma unroll
    for (int j = 0; j < 3; ++j) {
        v[j] = yr[lane + 64 * j];
        sum += v[j].x + v[j].y + v[j].z + v[j].w;
        ss  += v[j].x * v[j].x + v[j].y * v[j].y + v[j].z * v[j].z + v[j].w * v[j].w;
    }
#pragma unroll
    for (int msk = 1; msk < 64; msk <<= 1) {
        sum += __shfl_xor(sum, msk);
        ss  += __shfl_xor(ss,  msk);
    }
    float mu  = sum * (1.f / 768.f);
    float var = ss * (1.f / 768.f) - mu * mu;
    float is  = rsqrtf(var + 1e-5f);

    const float4* g4 = reinterpret_cast<const float4*>(gamma);
    const float4* b4 = reinterpret_cast<const float4*>(beta);
    float4* o4 = reinterpret_cast<float4*>(out + (size_t)row * D_MODEL);
#pragma unroll
    for (int j = 0; j < 3; ++j) {
        float4 g = g4[lane + 64 * j], b = b4[lane + 64 * j], r;
        r.x = (v[j].x - mu) * is * g.x + b.x;
        r.y = (v[j].y - mu) * is * g.y + b.y;
        r.z = (v[j].z - mu) * is * g.z + b.z;
        r.w = (v[j].w - mu) * is * g.w + b.w;
        o4[lane + 64 * j] = r;
    }
}

// ---------------------------------------------------------------------------
extern "C" void kernel_launch(void* const* d_in, const int* in_sizes, int n_in,
                              void* d_out, int out_size, void* d_ws, size_t ws_size,
                              hipStream_t stream)
{
    const float* Q     = (const float*)d_in[0];
    const float* Wq    = (const float*)d_in[1];
    const float* bq    = (const float*)d_in[2];
    const float* Wk    = (const float*)d_in[3];
    const float* bk    = (const float*)d_in[4];
    const float* Wv    = (const float*)d_in[5];
    const float* bv    = (const float*)d_in[6];
    const float* Wo    = (const float*)d_in[7];
    const float* bo    = (const float*)d_in[8];
    const float* gamma = (const float*)d_in[9];
    const float* beta  = (const float*)d_in[10];
    float* out = (float*)d_out;

    char* ws = (char*)d_ws;
    unsigned short* Xb    = (unsigned short*)(ws + 0);          // 6291456
    unsigned short* Wqb   = (unsigned short*)(ws + 6291456);    // 1179648 each
    unsigned short* Wkb   = (unsigned short*)(ws + 7471104);
    unsigned short* Wvb   = (unsigned short*)(ws + 8650752);
    unsigned short* Wob   = (unsigned short*)(ws + 9830400);
    unsigned short* qb    = (unsigned short*)(ws + 11010048);   // 6291456 each
    unsigned short* kb    = (unsigned short*)(ws + 17301504);
    unsigned short* vtb   = (unsigned short*)(ws + 23592960);
    unsigned short* attnb = (unsigned short*)(ws + 29884416);
    float*          Yf    = (float*)        (ws + 36175872);    // 12582912

    convert_kernel<<<5376, 256, 0, stream>>>(Q, Wq, Wk, Wv, Wo, Xb, Wqb, Wkb, Wvb, Wob);
    qkv_gemm_kernel<<<dim3(6, 32, 3), 256, 0, stream>>>(Xb, Wqb, Wkb, Wvb,
                                                        bq, bk, bv, qb, kb, vtb);
    attn_kernel<<<dim3(32, 24), 256, 0, stream>>>(qb, kb, vtb, attnb);
    oproj_kernel<<<dim3(6, 32), 256, 0, stream>>>(attnb, Wob, bo, Q, Yf);
    ln_kernel<<<1024, 256, 0, stream>>>(Yf, gamma, beta, out);
}

// Round 3
// 117.751 us; speedup vs baseline: 2.9953x; 2.8564x over previous
//
#include <hip/hip_runtime.h>
#include <hip/hip_bf16.h>

#define D_MODEL 768
#define S_LEN   2048
#define BATCH   2
#define NHEAD   12
#define DH      64
#define NTOK    (BATCH * S_LEN)   // 4096

typedef __attribute__((ext_vector_type(8))) short bf16x8;   // 8 bf16 in 4 VGPRs
typedef __attribute__((ext_vector_type(4))) float f32x4;

__device__ inline unsigned short f2bf(float f) {
    union { float f; unsigned u; } v; v.f = f;
    unsigned u = v.u;
    u += 0x7fffu + ((u >> 16) & 1u);
    return (unsigned short)(u >> 16);
}

__device__ inline unsigned pack_bf2(float a, float b) {
    union { __hip_bfloat162 h2; unsigned u; } cv;
    cv.h2 = __float22bfloat162_rn(make_float2(a, b));   // v_cvt_pk_bf16_f32
    return cv.u;
}

// async global->LDS, 16B per lane. LDS dest is wave-uniform base (+lane*16 by HW).
__device__ inline void stage16(const void* g, void* l) {
    __builtin_amdgcn_global_load_lds(
        (const __attribute__((address_space(1))) unsigned*)g,
        (__attribute__((address_space(3))) unsigned*)l, 16, 0, 0);
}

// ---------------------------------------------------------------------------
// Kernel 1: fp32 -> bf16 conversion of X and the 4 weight matrices
// ---------------------------------------------------------------------------
__global__ __launch_bounds__(256) void convert_kernel(
    const float* __restrict__ Q,
    const float* __restrict__ Wq, const float* __restrict__ Wk,
    const float* __restrict__ Wv, const float* __restrict__ Wo,
    unsigned short* __restrict__ Xb,
    unsigned short* __restrict__ Wqb, unsigned short* __restrict__ Wkb,
    unsigned short* __restrict__ Wvb, unsigned short* __restrict__ Wob)
{
    const int XV = NTOK * D_MODEL / 4;
    const int WV = D_MODEL * D_MODEL / 4;
    int idx = blockIdx.x * 256 + threadIdx.x;
    if (idx >= XV + 4 * WV) return;

    const float* src; unsigned short* dst; int off;
    if (idx < XV) { src = Q; dst = Xb; off = idx; }
    else {
        int i2 = idx - XV;
        int seg = i2 / WV; off = i2 - seg * WV;
        if      (seg == 0) { src = Wq; dst = Wqb; }
        else if (seg == 1) { src = Wk; dst = Wkb; }
        else if (seg == 2) { src = Wv; dst = Wvb; }
        else               { src = Wo; dst = Wob; }
    }
    float4 v = reinterpret_cast<const float4*>(src)[off];
    uint2 o;
    o.x = pack_bf2(v.x, v.y);
    o.y = pack_bf2(v.z, v.w);
    reinterpret_cast<uint2*>(dst)[off] = o;
}

// ===========================================================================
// Staged GEMM core pieces (BM=128, BN=64, BK=64).  LDS tiles hold bf16 with
// byte-swizzle  colb ^= (row&7)<<4  so stride-128B b128 reads are conflict-free.
// Staging pre-applies the inverse swizzle on the GLOBAL source address
// (global_load_lds writes linearly).  A,B row-major [rows][768].
// ===========================================================================
#define STAGE_TILE(glob, rowstrideB, row0, k0, ldsbase, nIss)                 \
    _Pragma("unroll")                                                          \
    for (int i = 0; i < (nIss); ++i) {                                         \
        int L = i * 4096 + wv * 1024 + lane * 16;                              \
        int row = L >> 7;                                                      \
        int colb = (L & 127) ^ ((row & 7) << 4);                               \
        stage16((const char*)(glob) + (size_t)((row0) + row) * (rowstrideB)    \
                    + ((k0) << 1) + colb,                                      \
                (char*)(ldsbase) + i * 4096 + wv * 1024);                      \
    }

// ---------------------------------------------------------------------------
// Kernel 2: fused QKV projection.  B = [Wq;Wk;Wv] contiguous (N=2304).
// grid (36, 32): x = col tile (64), y = row tile (128). 4 waves, 32x64/wave.
// ---------------------------------------------------------------------------
__global__ __launch_bounds__(256) void qkv_gemm_kernel(
    const unsigned short* __restrict__ Xb,
    const unsigned short* __restrict__ Wall,   // [2304][768]
    const float* __restrict__ bq, const float* __restrict__ bk,
    const float* __restrict__ bv,
    unsigned short* __restrict__ qb, unsigned short* __restrict__ kb,
    unsigned short* __restrict__ vtb)
{
    const int lane = threadIdx.x & 63;
    const int wv   = threadIdx.x >> 6;
    const int lr   = lane & 15;
    const int lg   = lane >> 4;
    const int row0g = blockIdx.y * 128;
    const int col0g = blockIdx.x * 64;          // in [0,2304)

    __shared__ __align__(16) unsigned short At[2][128 * 64];   // 32 KB
    __shared__ __align__(16) unsigned short Bt[2][64 * 64];    // 16 KB

    f32x4 acc[2][4] = {};

    STAGE_TILE(Xb,   1536, row0g, 0, At[0], 4);
    STAGE_TILE(Wall, 1536, col0g, 0, Bt[0], 2);
    __syncthreads();

    for (int s = 0; s < 12; ++s) {
        int cur = s & 1;
        if (s < 11) {
            STAGE_TILE(Xb,   1536, row0g, (s + 1) * 64, At[cur ^ 1], 4);
            STAGE_TILE(Wall, 1536, col0g, (s + 1) * 64, Bt[cur ^ 1], 2);
        }
        bf16x8 a[2][2], b[4][2];
#pragma unroll
        for (int m = 0; m < 2; ++m) {
            int row = wv * 32 + m * 16 + lr, sw = (row & 7) << 4;
#pragma unroll
            for (int ks = 0; ks < 2; ++ks)
                a[m][ks] = *reinterpret_cast<const bf16x8*>(
                    (const char*)At[cur] + row * 128 + ((ks * 64 + lg * 16) ^ sw));
        }
#pragma unroll
        for (int n = 0; n < 4; ++n) {
            int row = n * 16 + lr, sw = (row & 7) << 4;
#pragma unroll
            for (int ks = 0; ks < 2; ++ks)
                b[n][ks] = *reinterpret_cast<const bf16x8*>(
                    (const char*)Bt[cur] + row * 128 + ((ks * 64 + lg * 16) ^ sw));
        }
#pragma unroll
        for (int ks = 0; ks < 2; ++ks)
#pragma unroll
            for (int m = 0; m < 2; ++m)
#pragma unroll
                for (int n = 0; n < 4; ++n)
                    acc[m][n] = __builtin_amdgcn_mfma_f32_16x16x32_bf16(
                        a[m][ks], b[n][ks], acc[m][n], 0, 0, 0);
        __syncthreads();
    }

    // epilogue: which output (q/k/v) is uniform per block (2304/64=36, 12 per)
    const int which   = blockIdx.x / 12;
    const int colbase = (blockIdx.x % 12) * 64;
    const float* bias = (which == 0) ? bq : (which == 1) ? bk : bv;
#pragma unroll
    for (int m = 0; m < 2; ++m) {
#pragma unroll
        for (int n = 0; n < 4; ++n) {
            int col = colbase + n * 16 + lr;
            float bval = bias[col];
            int h = col >> 6, d = col & 63;
            int rowg = row0g + wv * 32 + m * 16 + lg * 4;
            int bb = rowg >> 11, s0 = rowg & 2047;
            if (which == 2) {
                uint2 w;
                w.x = pack_bf2(acc[m][n][0] + bval, acc[m][n][1] + bval);
                w.y = pack_bf2(acc[m][n][2] + bval, acc[m][n][3] + bval);
                *reinterpret_cast<uint2*>(
                    vtb + ((size_t)(bb * NHEAD + h) * DH + d) * S_LEN + s0) = w;
            } else {
                unsigned short* dst = (which == 0) ? qb : kb;
#pragma unroll
                for (int r = 0; r < 4; ++r)
                    dst[((size_t)(bb * NHEAD + h) * S_LEN + s0 + r) * DH + d] =
                        f2bf(acc[m][n][r] + bval);
            }
        }
    }
}

// ---------------------------------------------------------------------------
// Kernel 3: attention.  grid (32, 24), 4 waves; wave owns 16 q-rows.
// K,V^T chunks (64 keys) double-buffered in LDS via global_load_lds with
// pre-swizzled source; swapped-operand MFMA keeps softmax in-lane.
// ---------------------------------------------------------------------------
__global__ __launch_bounds__(256) void attn_kernel(
    const unsigned short* __restrict__ qb, const unsigned short* __restrict__ kb,
    const unsigned short* __restrict__ vtb,
    unsigned short* __restrict__ attnb)
{
    const int lane = threadIdx.x & 63;
    const int wv   = threadIdx.x >> 6;
    const int lr   = lane & 15;
    const int lg   = lane >> 4;
    const int bh   = blockIdx.y;
    const int h    = bh % NHEAD, bb = bh / NHEAD;
    const int q0   = blockIdx.x * 64 + wv * 16;

    __shared__ __align__(16) unsigned short Kt[2][64 * 64];   // 16 KB
    __shared__ __align__(16) unsigned short Vt[2][64 * 64];   // 16 KB
    __shared__ __align__(16) unsigned short PL[4][16][68];    // 8.7 KB

    const char* kbase = (const char*)(kb  + (size_t)bh * S_LEN * DH);   // [s][d]
    const char* vbase = (const char*)(vtb + (size_t)bh * DH * S_LEN);   // [d][s]
    const unsigned short* qptr = qb + ((size_t)bh * S_LEN + q0) * DH;

    bf16x8 bq0 = *reinterpret_cast<const bf16x8*>(qptr + (size_t)lr * DH + lg * 8);
    bf16x8 bq1 = *reinterpret_cast<const bf16x8*>(qptr + (size_t)lr * DH + 32 + lg * 8);

    float m = -1e30f, l = 0.f;
    f32x4 acc[4] = {};
    const float SC = 0.125f * 1.44269504088896f;

    // prologue: stage chunk 0
#pragma unroll
    for (int i = 0; i < 2; ++i) {
        int L = i * 4096 + wv * 1024 + lane * 16;
        int row = L >> 7, colb = (L & 127) ^ ((row & 7) << 4);
        stage16(kbase + (size_t)row * 128 + colb, (char*)Kt[0] + i * 4096 + wv * 1024);
        stage16(vbase + (size_t)row * 4096 + colb, (char*)Vt[0] + i * 4096 + wv * 1024);
    }
    __syncthreads();

    for (int ci = 0; ci < 32; ++ci) {
        const int cur = ci & 1;
        if (ci < 31) {
            int c1 = (ci + 1) * 64;
#pragma unroll
            for (int i = 0; i < 2; ++i) {
                int L = i * 4096 + wv * 1024 + lane * 16;
                int row = L >> 7, colb = (L & 127) ^ ((row & 7) << 4);
                stage16(kbase + (size_t)(c1 + row) * 128 + colb,
                        (char*)Kt[cur ^ 1] + i * 4096 + wv * 1024);
                stage16(vbase + (size_t)row * 4096 + (c1 << 1) + colb,
                        (char*)Vt[cur ^ 1] + i * 4096 + wv * 1024);
            }
        }

        // ---- S^T = K @ Q^T from LDS ----
        f32x4 s[4] = {};
#pragma unroll
        for (int kt = 0; kt < 4; ++kt) {
            int row = kt * 16 + lr, sw = (row & 7) << 4;
            bf16x8 ak0 = *reinterpret_cast<const bf16x8*>(
                (const char*)Kt[cur] + row * 128 + ((lg * 16) ^ sw));
            bf16x8 ak1 = *reinterpret_cast<const bf16x8*>(
                (const char*)Kt[cur] + row * 128 + ((64 + lg * 16) ^ sw));
            s[kt] = __builtin_amdgcn_mfma_f32_16x16x32_bf16(ak0, bq0, s[kt], 0, 0, 0);
            s[kt] = __builtin_amdgcn_mfma_f32_16x16x32_bf16(ak1, bq1, s[kt], 0, 0, 0);
        }

        // ---- V^T fragments from LDS ----
        bf16x8 av0[4], av1[4];
#pragma unroll
        for (int t = 0; t < 4; ++t) {
            int row = t * 16 + lr, sw = (row & 7) << 4;
            av0[t] = *reinterpret_cast<const bf16x8*>(
                (const char*)Vt[cur] + row * 128 + ((lg * 16) ^ sw));
            av1[t] = *reinterpret_cast<const bf16x8*>(
                (const char*)Vt[cur] + row * 128 + ((64 + lg * 16) ^ sw));
        }

        // ---- in-lane online softmax over 16 scores ----
        float p[16];
#pragma unroll
        for (int kt = 0; kt < 4; ++kt)
#pragma unroll
            for (int r = 0; r < 4; ++r) p[kt * 4 + r] = s[kt][r] * SC;

        float mx = fmaxf(fmaxf(fmaxf(p[0], p[1]), fmaxf(p[2], p[3])),
                         fmaxf(fmaxf(p[4], p[5]), fmaxf(p[6], p[7])));
        mx = fmaxf(mx, fmaxf(fmaxf(fmaxf(p[8], p[9]), fmaxf(p[10], p[11])),
                             fmaxf(fmaxf(p[12], p[13]), fmaxf(p[14], p[15]))));
        mx = fmaxf(mx, __shfl_xor(mx, 16));
        mx = fmaxf(mx, __shfl_xor(mx, 32));
        float mn = fmaxf(m, mx);

        float sum = 0.f;
#pragma unroll
        for (int j = 0; j < 16; ++j) {
            p[j] = __builtin_amdgcn_exp2f(p[j] - mn);
            sum += p[j];
        }
        sum += __shfl_xor(sum, 16);
        sum += __shfl_xor(sum, 32);
        float sf = __builtin_amdgcn_exp2f(m - mn);
        l = l * sf + sum; m = mn;
#pragma unroll
        for (int t = 0; t < 4; ++t) acc[t] *= sf;

        // ---- P -> LDS (wave-private, no barrier) ----
#pragma unroll
        for (int kt = 0; kt < 4; ++kt) {
            uint2 w;
            w.x = pack_bf2(p[kt * 4 + 0], p[kt * 4 + 1]);
            w.y = pack_bf2(p[kt * 4 + 2], p[kt * 4 + 3]);
            *reinterpret_cast<uint2*>(&PL[wv][lr][kt * 16 + lg * 4]) = w;
        }
        union { bf16x8 v; uint2 u[2]; } bp0, bp1;
        bp0.u[0] = *reinterpret_cast<const uint2*>(&PL[wv][lr][lg * 8]);
        bp0.u[1] = *reinterpret_cast<const uint2*>(&PL[wv][lr][lg * 8 + 4]);
        bp1.u[0] = *reinterpret_cast<const uint2*>(&PL[wv][lr][32 + lg * 8]);
        bp1.u[1] = *reinterpret_cast<const uint2*>(&PL[wv][lr][32 + lg * 8 + 4]);

        // ---- PV ----
#pragma unroll
        for (int t = 0; t < 4; ++t) {
            acc[t] = __builtin_amdgcn_mfma_f32_16x16x32_bf16(av0[t], bp0.v, acc[t], 0, 0, 0);
            acc[t] = __builtin_amdgcn_mfma_f32_16x16x32_bf16(av1[t], bp1.v, acc[t], 0, 0, 0);
        }
        __syncthreads();
    }

    float rl = 1.0f / l;
    size_t rowbase = ((size_t)(bb * S_LEN + q0 + lr)) * D_MODEL + h * DH;
#pragma unroll
    for (int t = 0; t < 4; ++t) {
        unsigned w0 = pack_bf2(acc[t][0] * rl, acc[t][1] * rl);
        unsigned w1 = pack_bf2(acc[t][2] * rl, acc[t][3] * rl);
        *reinterpret_cast<unsigned*>(attnb + rowbase + t * 16 + lg * 4)     = w0;
        *reinterpret_cast<unsigned*>(attnb + rowbase + t * 16 + lg * 4 + 2) = w1;
    }
}

// ---------------------------------------------------------------------------
// Kernel 4: output projection + bias + residual -> fp32 Y.  Same GEMM core.
// grid (12, 32).
// ---------------------------------------------------------------------------
__global__ __launch_bounds__(256) void oproj_kernel(
    const unsigned short* __restrict__ attnb, const unsigned short* __restrict__ Wob,
    const float* __restrict__ bo, const float* __restrict__ Qres,
    float* __restrict__ Y)
{
    const int lane = threadIdx.x & 63;
    const int wv   = threadIdx.x >> 6;
    const int lr   = lane & 15;
    const int lg   = lane >> 4;
    const int row0g = blockIdx.y * 128;
    const int col0g = blockIdx.x * 64;

    __shared__ __align__(16) unsigned short At[2][128 * 64];
    __shared__ __align__(16) unsigned short Bt[2][64 * 64];

    f32x4 acc[2][4] = {};

    STAGE_TILE(attnb, 1536, row0g, 0, At[0], 4);
    STAGE_TILE(Wob,   1536, col0g, 0, Bt[0], 2);
    __syncthreads();

    for (int s = 0; s < 12; ++s) {
        int cur = s & 1;
        if (s < 11) {
            STAGE_TILE(attnb, 1536, row0g, (s + 1) * 64, At[cur ^ 1], 4);
            STAGE_TILE(Wob,   1536, col0g, (s + 1) * 64, Bt[cur ^ 1], 2);
        }
        bf16x8 a[2][2], b[4][2];
#pragma unroll
        for (int m = 0; m < 2; ++m) {
            int row = wv * 32 + m * 16 + lr, sw = (row & 7) << 4;
#pragma unroll
            for (int ks = 0; ks < 2; ++ks)
                a[m][ks] = *reinterpret_cast<const bf16x8*>(
                    (const char*)At[cur] + row * 128 + ((ks * 64 + lg * 16) ^ sw));
        }
#pragma unroll
        for (int n = 0; n < 4; ++n) {
            int row = n * 16 + lr, sw = (row & 7) << 4;
#pragma unroll
            for (int ks = 0; ks < 2; ++ks)
                b[n][ks] = *reinterpret_cast<const bf16x8*>(
                    (const char*)Bt[cur] + row * 128 + ((ks * 64 + lg * 16) ^ sw));
        }
#pragma unroll
        for (int ks = 0; ks < 2; ++ks)
#pragma unroll
            for (int m = 0; m < 2; ++m)
#pragma unroll
                for (int n = 0; n < 4; ++n)
                    acc[m][n] = __builtin_amdgcn_mfma_f32_16x16x32_bf16(
                        a[m][ks], b[n][ks], acc[m][n], 0, 0, 0);
        __syncthreads();
    }

#pragma unroll
    for (int m = 0; m < 2; ++m)
#pragma unroll
        for (int n = 0; n < 4; ++n) {
            int col = col0g + n * 16 + lr;
            float bval = bo[col];
#pragma unroll
            for (int r = 0; r < 4; ++r) {
                int row = row0g + wv * 32 + m * 16 + lg * 4 + r;
                size_t off = (size_t)row * D_MODEL + col;
                Y[off] = acc[m][n][r] + bval + Qres[off];
            }
        }
}

// ---------------------------------------------------------------------------
// Kernel 5: LayerNorm per row.
// ---------------------------------------------------------------------------
__global__ __launch_bounds__(256) void ln_kernel(
    const float* __restrict__ Y,
    const float* __restrict__ gamma, const float* __restrict__ beta,
    float* __restrict__ out)
{
    const int lane = threadIdx.x & 63;
    const int row  = blockIdx.x * 4 + (threadIdx.x >> 6);
    const float4* yr = reinterpret_cast<const float4*>(Y + (size_t)row * D_MODEL);

    float4 v[3];
    float sum = 0.f, ss = 0.f;
#pragma unroll
    for (int j = 0; j < 3; ++j) {
        v[j] = yr[lane + 64 * j];
        sum += v[j].x + v[j].y + v[j].z + v[j].w;
        ss  += v[j].x * v[j].x + v[j].y * v[j].y + v[j].z * v[j].z + v[j].w * v[j].w;
    }
#pragma unroll
    for (int msk = 1; msk < 64; msk <<= 1) {
        sum += __shfl_xor(sum, msk);
        ss  += __shfl_xor(ss,  msk);
    }
    float mu  = sum * (1.f / 768.f);
    float var = ss * (1.f / 768.f) - mu * mu;
    float is  = rsqrtf(var + 1e-5f);

    const float4* g4 = reinterpret_cast<const float4*>(gamma);
    const float4* b4 = reinterpret_cast<const float4*>(beta);
    float4* o4 = reinterpret_cast<float4*>(out + (size_t)row * D_MODEL);
#pragma unroll
    for (int j = 0; j < 3; ++j) {
        float4 g = g4[lane + 64 * j], b = b4[lane + 64 * j], r;
        r.x = (v[j].x - mu) * is * g.x + b.x;
        r.y = (v[j].y - mu) * is * g.y + b.y;
        r.z = (v[j].z - mu) * is * g.z + b.z;
        r.w = (v[j].w - mu) * is * g.w + b.w;
        o4[lane + 64 * j] = r;
    }
}

// ---------------------------------------------------------------------------
extern "C" void kernel_launch(void* const* d_in, const int* in_sizes, int n_in,
                              void* d_out, int out_size, void* d_ws, size_t ws_size,
                              hipStream_t stream)
{
    const float* Q     = (const float*)d_in[0];
    const float* Wq    = (const float*)d_in[1];
    const float* bq    = (const float*)d_in[2];
    const float* Wk    = (const float*)d_in[3];
    const float* bk    = (const float*)d_in[4];
    const float* Wv    = (const float*)d_in[5];
    const float* bv    = (const float*)d_in[6];
    const float* Wo    = (const float*)d_in[7];
    const float* bo    = (const float*)d_in[8];
    const float* gamma = (const float*)d_in[9];
    const float* beta  = (const float*)d_in[10];
    float* out = (float*)d_out;

    char* ws = (char*)d_ws;
    unsigned short* Xb    = (unsigned short*)(ws + 0);          // 6291456
    unsigned short* Wqb   = (unsigned short*)(ws + 6291456);    // Wq,Wk,Wv contiguous
    unsigned short* Wkb   = (unsigned short*)(ws + 7471104);
    unsigned short* Wvb   = (unsigned short*)(ws + 8650752);
    unsigned short* Wob   = (unsigned short*)(ws + 9830400);
    unsigned short* qb    = (unsigned short*)(ws + 11010048);
    unsigned short* kb    = (unsigned short*)(ws + 17301504);
    unsigned short* vtb   = (unsigned short*)(ws + 23592960);
    unsigned short* attnb = (unsigned short*)(ws + 29884416);
    float*          Yf    = (float*)        (ws + 36175872);

    convert_kernel<<<5376, 256, 0, stream>>>(Q, Wq, Wk, Wv, Wo, Xb, Wqb, Wkb, Wvb, Wob);
    qkv_gemm_kernel<<<dim3(36, 32), 256, 0, stream>>>(Xb, Wqb, bq, bk, bv, qb, kb, vtb);
    attn_kernel<<<dim3(32, 24), 256, 0, stream>>>(qb, kb, vtb, attnb);
    oproj_kernel<<<dim3(12, 32), 256, 0, stream>>>(attnb, Wob, bo, Q, Yf);
    ln_kernel<<<1024, 256, 0, stream>>>(Yf, gamma, beta, out);
}

// Round 5
// 110.935 us; speedup vs baseline: 3.1794x; 1.0614x over previous
//
#include <hip/hip_runtime.h>
#include <hip/hip_bf16.h>

#define D_MODEL 768
#define S_LEN   2048
#define BATCH   2
#define NHEAD   12
#define DH      64
#define NTOK    (BATCH * S_LEN)   // 4096

typedef __attribute__((ext_vector_type(8))) short bf16x8;   // 8 bf16 in 4 VGPRs
typedef __attribute__((ext_vector_type(4))) float f32x4;

__device__ inline unsigned short f2bf(float f) {
    union { float f; unsigned u; } v; v.f = f;
    unsigned u = v.u;
    u += 0x7fffu + ((u >> 16) & 1u);
    return (unsigned short)(u >> 16);
}

__device__ inline unsigned pack_bf2(float a, float b) {
    union { __hip_bfloat162 h2; unsigned u; } cv;
    cv.h2 = __float22bfloat162_rn(make_float2(a, b));   // v_cvt_pk_bf16_f32
    return cv.u;
}

// async global->LDS, 16B per lane. LDS dest is wave-uniform base (+lane*16 by HW).
__device__ inline void stage16(const void* g, void* l) {
    __builtin_amdgcn_global_load_lds(
        (const __attribute__((address_space(1))) unsigned*)g,
        (__attribute__((address_space(3))) unsigned*)l, 16, 0, 0);
}

// ---------------------------------------------------------------------------
// Kernel 1: fp32 -> bf16 conversion of X and the 4 weight matrices
// ---------------------------------------------------------------------------
__global__ __launch_bounds__(256) void convert_kernel(
    const float* __restrict__ Q,
    const float* __restrict__ Wq, const float* __restrict__ Wk,
    const float* __restrict__ Wv, const float* __restrict__ Wo,
    unsigned short* __restrict__ Xb,
    unsigned short* __restrict__ Wqb, unsigned short* __restrict__ Wkb,
    unsigned short* __restrict__ Wvb, unsigned short* __restrict__ Wob)
{
    const int XV = NTOK * D_MODEL / 4;
    const int WV = D_MODEL * D_MODEL / 4;
    int idx = blockIdx.x * 256 + threadIdx.x;
    if (idx >= XV + 4 * WV) return;

    const float* src; unsigned short* dst; int off;
    if (idx < XV) { src = Q; dst = Xb; off = idx; }
    else {
        int i2 = idx - XV;
        int seg = i2 / WV; off = i2 - seg * WV;
        if      (seg == 0) { src = Wq; dst = Wqb; }
        else if (seg == 1) { src = Wk; dst = Wkb; }
        else if (seg == 2) { src = Wv; dst = Wvb; }
        else               { src = Wo; dst = Wob; }
    }
    float4 v = reinterpret_cast<const float4*>(src)[off];
    uint2 o;
    o.x = pack_bf2(v.x, v.y);
    o.y = pack_bf2(v.z, v.w);
    reinterpret_cast<uint2*>(dst)[off] = o;
}

// ===========================================================================
// Staged GEMM pieces (BM=128, BN=64, BK=64), XOR-swizzled LDS via
// pre-swizzled global source (global_load_lds writes linearly).
// ===========================================================================
#define STAGE_TILE(glob, rowstrideB, row0, k0, ldsbase, nIss)                 \
    _Pragma("unroll")                                                          \
    for (int i = 0; i < (nIss); ++i) {                                         \
        int L = i * 4096 + wv * 1024 + lane * 16;                              \
        int row = L >> 7;                                                      \
        int colb = (L & 127) ^ ((row & 7) << 4);                               \
        stage16((const char*)(glob) + (size_t)((row0) + row) * (rowstrideB)    \
                    + ((k0) << 1) + colb,                                      \
                (char*)(ldsbase) + i * 4096 + wv * 1024);                      \
    }

// ---------------------------------------------------------------------------
// Kernel 2: fused QKV projection.  B = [Wq;Wk;Wv] contiguous (N=2304).
// ---------------------------------------------------------------------------
__global__ __launch_bounds__(256) void qkv_gemm_kernel(
    const unsigned short* __restrict__ Xb,
    const unsigned short* __restrict__ Wall,   // [2304][768]
    const float* __restrict__ bq, const float* __restrict__ bk,
    const float* __restrict__ bv,
    unsigned short* __restrict__ qb, unsigned short* __restrict__ kb,
    unsigned short* __restrict__ vtb)
{
    const int lane = threadIdx.x & 63;
    const int wv   = threadIdx.x >> 6;
    const int lr   = lane & 15;
    const int lg   = lane >> 4;
    const int row0g = blockIdx.y * 128;
    const int col0g = blockIdx.x * 64;

    __shared__ __align__(16) unsigned short At[2][128 * 64];
    __shared__ __align__(16) unsigned short Bt[2][64 * 64];

    f32x4 acc[2][4] = {};

    STAGE_TILE(Xb,   1536, row0g, 0, At[0], 4);
    STAGE_TILE(Wall, 1536, col0g, 0, Bt[0], 2);
    __syncthreads();

    for (int s = 0; s < 12; ++s) {
        int cur = s & 1;
        if (s < 11) {
            STAGE_TILE(Xb,   1536, row0g, (s + 1) * 64, At[cur ^ 1], 4);
            STAGE_TILE(Wall, 1536, col0g, (s + 1) * 64, Bt[cur ^ 1], 2);
        }
        bf16x8 a[2][2], b[4][2];
#pragma unroll
        for (int m = 0; m < 2; ++m) {
            int row = wv * 32 + m * 16 + lr, sw = (row & 7) << 4;
#pragma unroll
            for (int ks = 0; ks < 2; ++ks)
                a[m][ks] = *reinterpret_cast<const bf16x8*>(
                    (const char*)At[cur] + row * 128 + ((ks * 64 + lg * 16) ^ sw));
        }
#pragma unroll
        for (int n = 0; n < 4; ++n) {
            int row = n * 16 + lr, sw = (row & 7) << 4;
#pragma unroll
            for (int ks = 0; ks < 2; ++ks)
                b[n][ks] = *reinterpret_cast<const bf16x8*>(
                    (const char*)Bt[cur] + row * 128 + ((ks * 64 + lg * 16) ^ sw));
        }
#pragma unroll
        for (int ks = 0; ks < 2; ++ks)
#pragma unroll
            for (int m = 0; m < 2; ++m)
#pragma unroll
                for (int n = 0; n < 4; ++n)
                    acc[m][n] = __builtin_amdgcn_mfma_f32_16x16x32_bf16(
                        a[m][ks], b[n][ks], acc[m][n], 0, 0, 0);
        __syncthreads();
    }

    const int which   = blockIdx.x / 12;
    const int colbase = (blockIdx.x % 12) * 64;
    const float* bias = (which == 0) ? bq : (which == 1) ? bk : bv;
#pragma unroll
    for (int m = 0; m < 2; ++m) {
#pragma unroll
        for (int n = 0; n < 4; ++n) {
            int col = colbase + n * 16 + lr;
            float bval = bias[col];
            int h = col >> 6, d = col & 63;
            int rowg = row0g + wv * 32 + m * 16 + lg * 4;
            int bb = rowg >> 11, s0 = rowg & 2047;
            if (which == 2) {
                uint2 w;
                w.x = pack_bf2(acc[m][n][0] + bval, acc[m][n][1] + bval);
                w.y = pack_bf2(acc[m][n][2] + bval, acc[m][n][3] + bval);
                *reinterpret_cast<uint2*>(
                    vtb + ((size_t)(bb * NHEAD + h) * DH + d) * S_LEN + s0) = w;
            } else {
                unsigned short* dst = (which == 0) ? qb : kb;
#pragma unroll
                for (int r = 0; r < 4; ++r)
                    dst[((size_t)(bb * NHEAD + h) * S_LEN + s0 + r) * DH + d] =
                        f2bf(acc[m][n][r] + bval);
            }
        }
    }
}

// ---------------------------------------------------------------------------
// Kernel 3: attention.  grid (32, 24), 4 waves; wave owns 16 q-rows.
// Hoisted addressing (XOR-safe: second half-fragment via oD = (o0^64)-o0),
// defer-max online softmax, setprio'd MFMA clusters.
// ---------------------------------------------------------------------------
#define ATTN_CHUNK(P, CI)                                                      \
    {                                                                          \
        if ((CI) < 31) {                                                       \
            stage16(kg0, sdK[(P) ^ 1]);                                        \
            stage16(kg1, sdK[(P) ^ 1] + 4096);                                 \
            stage16(vg0, sdV[(P) ^ 1]);                                        \
            stage16(vg1, sdV[(P) ^ 1] + 4096);                                 \
            kg0 += 8192; kg1 += 8192; vg0 += 128; vg1 += 128;                  \
        }                                                                      \
        f32x4 s[4] = {};                                                       \
        __builtin_amdgcn_s_setprio(1);                                         \
        _Pragma("unroll")                                                      \
        for (int kt = 0; kt < 4; ++kt) {                                       \
            bf16x8 ak0 = *(const bf16x8*)(rdK[P] + kt * 2048);                 \
            bf16x8 ak1 = *(const bf16x8*)(rdK[P] + kt * 2048 + oD);            \
            s[kt] = __builtin_amdgcn_mfma_f32_16x16x32_bf16(ak0, bq0, s[kt], 0, 0, 0); \
            s[kt] = __builtin_amdgcn_mfma_f32_16x16x32_bf16(ak1, bq1, s[kt], 0, 0, 0); \
        }                                                                      \
        __builtin_amdgcn_s_setprio(0);                                         \
        bf16x8 av0[4], av1[4];                                                 \
        _Pragma("unroll")                                                      \
        for (int t = 0; t < 4; ++t) {                                          \
            av0[t] = *(const bf16x8*)(rdV[P] + t * 2048);                      \
            av1[t] = *(const bf16x8*)(rdV[P] + t * 2048 + oD);                 \
        }                                                                      \
        float mxr = fmaxf(fmaxf(fmaxf(s[0][0], s[0][1]), fmaxf(s[0][2], s[0][3])), \
                          fmaxf(fmaxf(s[1][0], s[1][1]), fmaxf(s[1][2], s[1][3]))); \
        mxr = fmaxf(mxr, fmaxf(fmaxf(fmaxf(s[2][0], s[2][1]), fmaxf(s[2][2], s[2][3])), \
                               fmaxf(fmaxf(s[3][0], s[3][1]), fmaxf(s[3][2], s[3][3])))); \
        mxr = fmaxf(mxr, __shfl_xor(mxr, 16));                                 \
        mxr = fmaxf(mxr, __shfl_xor(mxr, 32));                                 \
        float mxs = mxr * SC;                                                  \
        if (__any(mxs > m + 8.0f)) {                                           \
            float mn = fmaxf(m, mxs);                                          \
            float sf = __builtin_amdgcn_exp2f(m - mn);                         \
            m = mn; l *= sf;                                                   \
            _Pragma("unroll")                                                  \
            for (int t = 0; t < 4; ++t) acc[t] *= sf;                          \
        }                                                                      \
        float p[16];                                                           \
        _Pragma("unroll")                                                      \
        for (int kt = 0; kt < 4; ++kt)                                         \
            _Pragma("unroll")                                                  \
            for (int r = 0; r < 4; ++r)                                        \
                p[kt * 4 + r] = __builtin_amdgcn_exp2f(fmaf(s[kt][r], SC, -m)); \
        float sum = ((p[0] + p[1]) + (p[2] + p[3])) + ((p[4] + p[5]) + (p[6] + p[7])); \
        sum += ((p[8] + p[9]) + (p[10] + p[11])) + ((p[12] + p[13]) + (p[14] + p[15])); \
        sum += __shfl_xor(sum, 16);                                            \
        sum += __shfl_xor(sum, 32);                                            \
        l += sum;                                                              \
        _Pragma("unroll")                                                      \
        for (int kt = 0; kt < 4; ++kt) {                                       \
            uint2 w;                                                           \
            w.x = pack_bf2(p[kt * 4 + 0], p[kt * 4 + 1]);                      \
            w.y = pack_bf2(p[kt * 4 + 2], p[kt * 4 + 3]);                      \
            *(uint2*)(plw + ((kt * 32 + lg * 8) ^ swr)) = w;                   \
        }                                                                      \
        union { bf16x8 v; uint2 u[2]; } bp0, bp1;                              \
        bp0.u[0] = *(const uint2*)(plr);                                       \
        bp0.u[1] = *(const uint2*)(plr + 8);                                   \
        bp1.u[0] = *(const uint2*)(plr + oD);                                  \
        bp1.u[1] = *(const uint2*)(plr + oD + 8);                              \
        __builtin_amdgcn_s_setprio(1);                                         \
        _Pragma("unroll")                                                      \
        for (int t = 0; t < 4; ++t) {                                          \
            acc[t] = __builtin_amdgcn_mfma_f32_16x16x32_bf16(av0[t], bp0.v, acc[t], 0, 0, 0); \
            acc[t] = __builtin_amdgcn_mfma_f32_16x16x32_bf16(av1[t], bp1.v, acc[t], 0, 0, 0); \
        }                                                                      \
        __builtin_amdgcn_s_setprio(0);                                         \
        __syncthreads();                                                       \
    }

__global__ __launch_bounds__(256) void attn_kernel(
    const unsigned short* __restrict__ qb, const unsigned short* __restrict__ kb,
    const unsigned short* __restrict__ vtb,
    unsigned short* __restrict__ attnb)
{
    const int lane = threadIdx.x & 63;
    const int wv   = threadIdx.x >> 6;
    const int lr   = lane & 15;
    const int lg   = lane >> 4;
    const int bh   = blockIdx.y;
    const int h    = bh % NHEAD, bb = bh / NHEAD;
    const int q0   = blockIdx.x * 64 + wv * 16;

    __shared__ __align__(16) unsigned short Kt[2][64 * 64];   // 16 KB
    __shared__ __align__(16) unsigned short Vt[2][64 * 64];   // 16 KB
    __shared__ __align__(16) unsigned short PL[4][16][64];    // 8 KB (XOR-swz)

    const char* kbase = (const char*)(kb  + (size_t)bh * S_LEN * DH);
    const char* vbase = (const char*)(vtb + (size_t)bh * DH * S_LEN);
    const unsigned short* qptr = qb + ((size_t)bh * S_LEN + q0) * DH;

    bf16x8 bq0 = *reinterpret_cast<const bf16x8*>(qptr + (size_t)lr * DH + lg * 8);
    bf16x8 bq1 = *reinterpret_cast<const bf16x8*>(qptr + (size_t)lr * DH + 32 + lg * 8);

    // hoisted addressing ----------------------------------------------------
    const int swr = (lr & 7) << 4;
    const int o0  = (lg * 16) ^ swr;          // swizzled in-row offset, half 0
    const int oD  = (o0 ^ 64) - o0;           // XOR-safe delta to half 1 (= +/-64)
    const int L1  = wv * 1024 + lane * 16;
    const int r1  = L1 >> 7;
    const int cb1 = (L1 & 127) ^ ((r1 & 7) << 4);

    const char* kg0 = kbase + (size_t)r1 * 128 + cb1;
    const char* kg1 = kbase + (size_t)(32 + r1) * 128 + cb1;
    const char* vg0 = vbase + (size_t)r1 * 4096 + cb1;
    const char* vg1 = vbase + (size_t)(32 + r1) * 4096 + cb1;

    char* sdK[2] = { (char*)Kt[0] + wv * 1024, (char*)Kt[1] + wv * 1024 };
    char* sdV[2] = { (char*)Vt[0] + wv * 1024, (char*)Vt[1] + wv * 1024 };
    const char* rdK[2] = {
        (const char*)Kt[0] + lr * 128 + o0,
        (const char*)Kt[1] + lr * 128 + o0 };
    const char* rdV[2] = {
        (const char*)Vt[0] + lr * 128 + o0,
        (const char*)Vt[1] + lr * 128 + o0 };
    char* plw = (char*)PL + wv * 2048 + lr * 128;          // write base (full XOR inside)
    const char* plr = plw + o0;                            // read base

    float m = -1e30f, l = 0.f;
    f32x4 acc[4] = {};
    const float SC = 0.125f * 1.44269504088896f;

    // prologue: stage chunk 0 into buffer 0
    stage16(kg0, sdK[0]); stage16(kg1, sdK[0] + 4096);
    stage16(vg0, sdV[0]); stage16(vg1, sdV[0] + 4096);
    kg0 += 8192; kg1 += 8192; vg0 += 128; vg1 += 128;
    __syncthreads();

    for (int it = 0; it < 16; ++it) {
        ATTN_CHUNK(0, it * 2);
        ATTN_CHUNK(1, it * 2 + 1);
    }

    float rl = 1.0f / l;
    size_t rowbase = ((size_t)(bb * S_LEN + q0 + lr)) * D_MODEL + h * DH;
#pragma unroll
    for (int t = 0; t < 4; ++t) {
        unsigned w0 = pack_bf2(acc[t][0] * rl, acc[t][1] * rl);
        unsigned w1 = pack_bf2(acc[t][2] * rl, acc[t][3] * rl);
        *reinterpret_cast<unsigned*>(attnb + rowbase + t * 16 + lg * 4)     = w0;
        *reinterpret_cast<unsigned*>(attnb + rowbase + t * 16 + lg * 4 + 2) = w1;
    }
}

// ---------------------------------------------------------------------------
// Kernel 4: output projection + bias + residual -> fp32 Y.
// ---------------------------------------------------------------------------
__global__ __launch_bounds__(256) void oproj_kernel(
    const unsigned short* __restrict__ attnb, const unsigned short* __restrict__ Wob,
    const float* __restrict__ bo, const float* __restrict__ Qres,
    float* __restrict__ Y)
{
    const int lane = threadIdx.x & 63;
    const int wv   = threadIdx.x >> 6;
    const int lr   = lane & 15;
    const int lg   = lane >> 4;
    const int row0g = blockIdx.y * 128;
    const int col0g = blockIdx.x * 64;

    __shared__ __align__(16) unsigned short At[2][128 * 64];
    __shared__ __align__(16) unsigned short Bt[2][64 * 64];

    f32x4 acc[2][4] = {};

    STAGE_TILE(attnb, 1536, row0g, 0, At[0], 4);
    STAGE_TILE(Wob,   1536, col0g, 0, Bt[0], 2);
    __syncthreads();

    for (int s = 0; s < 12; ++s) {
        int cur = s & 1;
        if (s < 11) {
            STAGE_TILE(attnb, 1536, row0g, (s + 1) * 64, At[cur ^ 1], 4);
            STAGE_TILE(Wob,   1536, col0g, (s + 1) * 64, Bt[cur ^ 1], 2);
        }
        bf16x8 a[2][2], b[4][2];
#pragma unroll
        for (int m = 0; m < 2; ++m) {
            int row = wv * 32 + m * 16 + lr, sw = (row & 7) << 4;
#pragma unroll
            for (int ks = 0; ks < 2; ++ks)
                a[m][ks] = *reinterpret_cast<const bf16x8*>(
                    (const char*)At[cur] + row * 128 + ((ks * 64 + lg * 16) ^ sw));
        }
#pragma unroll
        for (int n = 0; n < 4; ++n) {
            int row = n * 16 + lr, sw = (row & 7) << 4;
#pragma unroll
            for (int ks = 0; ks < 2; ++ks)
                b[n][ks] = *reinterpret_cast<const bf16x8*>(
                    (const char*)Bt[cur] + row * 128 + ((ks * 64 + lg * 16) ^ sw));
        }
#pragma unroll
        for (int ks = 0; ks < 2; ++ks)
#pragma unroll
            for (int m = 0; m < 2; ++m)
#pragma unroll
                for (int n = 0; n < 4; ++n)
                    acc[m][n] = __builtin_amdgcn_mfma_f32_16x16x32_bf16(
                        a[m][ks], b[n][ks], acc[m][n], 0, 0, 0);
        __syncthreads();
    }

#pragma unroll
    for (int m = 0; m < 2; ++m)
#pragma unroll
        for (int n = 0; n < 4; ++n) {
            int col = col0g + n * 16 + lr;
            float bval = bo[col];
#pragma unroll
            for (int r = 0; r < 4; ++r) {
                int row = row0g + wv * 32 + m * 16 + lg * 4 + r;
                size_t off = (size_t)row * D_MODEL + col;
                Y[off] = acc[m][n][r] + bval + Qres[off];
            }
        }
}

// ---------------------------------------------------------------------------
// Kernel 5: LayerNorm per row.
// ---------------------------------------------------------------------------
__global__ __launch_bounds__(256) void ln_kernel(
    const float* __restrict__ Y,
    const float* __restrict__ gamma, const float* __restrict__ beta,
    float* __restrict__ out)
{
    const int lane = threadIdx.x & 63;
    const int row  = blockIdx.x * 4 + (threadIdx.x >> 6);
    const float4* yr = reinterpret_cast<const float4*>(Y + (size_t)row * D_MODEL);

    float4 v[3];
    float sum = 0.f, ss = 0.f;
#pragma unroll
    for (int j = 0; j < 3; ++j) {
        v[j] = yr[lane + 64 * j];
        sum += v[j].x + v[j].y + v[j].z + v[j].w;
        ss  += v[j].x * v[j].x + v[j].y * v[j].y + v[j].z * v[j].z + v[j].w * v[j].w;
    }
#pragma unroll
    for (int msk = 1; msk < 64; msk <<= 1) {
        sum += __shfl_xor(sum, msk);
        ss  += __shfl_xor(ss,  msk);
    }
    float mu  = sum * (1.f / 768.f);
    float var = ss * (1.f / 768.f) - mu * mu;
    float is  = rsqrtf(var + 1e-5f);

    const float4* g4 = reinterpret_cast<const float4*>(gamma);
    const float4* b4 = reinterpret_cast<const float4*>(beta);
    float4* o4 = reinterpret_cast<float4*>(out + (size_t)row * D_MODEL);
#pragma unroll
    for (int j = 0; j < 3; ++j) {
        float4 g = g4[lane + 64 * j], b = b4[lane + 64 * j], r;
        r.x = (v[j].x - mu) * is * g.x + b.x;
        r.y = (v[j].y - mu) * is * g.y + b.y;
        r.z = (v[j].z - mu) * is * g.z + b.z;
        r.w = (v[j].w - mu) * is * g.w + b.w;
        o4[lane + 64 * j] = r;
    }
}

// ---------------------------------------------------------------------------
extern "C" void kernel_launch(void* const* d_in, const int* in_sizes, int n_in,
                              void* d_out, int out_size, void* d_ws, size_t ws_size,
                              hipStream_t stream)
{
    const float* Q     = (const float*)d_in[0];
    const float* Wq    = (const float*)d_in[1];
    const float* bq    = (const float*)d_in[2];
    const float* Wk    = (const float*)d_in[3];
    const float* bk    = (const float*)d_in[4];
    const float* Wv    = (const float*)d_in[5];
    const float* bv    = (const float*)d_in[6];
    const float* Wo    = (const float*)d_in[7];
    const float* bo    = (const float*)d_in[8];
    const float* gamma = (const float*)d_in[9];
    const float* beta  = (const float*)d_in[10];
    float* out = (float*)d_out;

    char* ws = (char*)d_ws;
    unsigned short* Xb    = (unsigned short*)(ws + 0);
    unsigned short* Wqb   = (unsigned short*)(ws + 6291456);    // Wq,Wk,Wv contiguous
    unsigned short* Wkb   = (unsigned short*)(ws + 7471104);
    unsigned short* Wvb   = (unsigned short*)(ws + 8650752);
    unsigned short* Wob   = (unsigned short*)(ws + 9830400);
    unsigned short* qb    = (unsigned short*)(ws + 11010048);
    unsigned short* kb    = (unsigned short*)(ws + 17301504);
    unsigned short* vtb   = (unsigned short*)(ws + 23592960);
    unsigned short* attnb = (unsigned short*)(ws + 29884416);
    float*          Yf    = (float*)        (ws + 36175872);

    convert_kernel<<<5376, 256, 0, stream>>>(Q, Wq, Wk, Wv, Wo, Xb, Wqb, Wkb, Wvb, Wob);
    qkv_gemm_kernel<<<dim3(36, 32), 256, 0, stream>>>(Xb, Wqb, bq, bk, bv, qb, kb, vtb);
    attn_kernel<<<dim3(32, 24), 256, 0, stream>>>(qb, kb, vtb, attnb);
    oproj_kernel<<<dim3(12, 32), 256, 0, stream>>>(attnb, Wob, bo, Q, Yf);
    ln_kernel<<<1024, 256, 0, stream>>>(Yf, gamma, beta, out);
}